// Round 8
// baseline (788.368 us; speedup 1.0000x reference)
//
#include <hip/hip_runtime.h>

// DiffeomorphicLearnerTorch, R13 — barrier-free wave-streaming.
// R8-R12 post-mortem: three structural fixes (reg diet, operand L2->LDS,
// counted-vmcnt 4-deep ring) all ~neutral; MfmaUtil pinned 22-24%. Per-CU
// pipe audit: MFMA 1536 cyc/tile vs 6000 wall, LDS ~1536, VALU ~1000, L2
// ~600 — all <=26%. The wall is the BLOCK STRUCTURE: barrier-locked waves
// convoy (2 blocks/CU anti-phase), barrier release -> LDS burst, S->exp
// full-join with nothing to interleave. The invariant across all variants.
// R13 deletes the coupling: sZj was a LINEAR copy of the Zf chunk stream,
// so S's a-frags are read DIRECTLY from global/L2 via a rolling 8-frag
// register window (issue f+8, consume f; static zw[ks&7] indices). No LDS,
// no s_barrier, no global_load_lds in k_flash — every wave independent
// (attn-decode regime: 2 waves/SIMD self-hide latency, setprio pays).
// L1 dedups the 4 waves/block reading the same Zj stream. Window overrun
// at tile 15 reads <=8KB past Zf into erow (same ws, never consumed).
// Math identical to R10 (verified, absmax 0.015625).
// Frag-linear layouts (verified R4/R5):
//   Zf  [128 jblk][16 ks][64 lane]x8 bf16   (frag f at chunk_base + f*512 + lane*8)
//   ATf [t][8 dblk][256 jb][64 lane]x8 bf16
// eperm = erow permuted to S^T reg order (pidx).

#define N_PTS 4096
#define DIM   256
#define DT_C  0.125f
#define C1    (1.0f/512.0f)
#define C2    (1.0f/256.0f)

typedef __bf16 bf16x8 __attribute__((ext_vector_type(8)));
typedef float  f32x16 __attribute__((ext_vector_type(16)));
typedef float  f32x4v __attribute__((ext_vector_type(4)));
typedef unsigned int   u32x4 __attribute__((ext_vector_type(4)));
typedef unsigned short u16x8 __attribute__((ext_vector_type(8)));

__device__ __forceinline__ unsigned short f2bf(float f) {
  unsigned int u = __builtin_bit_cast(unsigned int, f);
  u += 0x7fffu + ((u >> 16) & 1u);          // RNE
  return (unsigned short)(u >> 16);
}
__device__ __forceinline__ float bf2f(unsigned short s) {
  unsigned int u = ((unsigned int)s) << 16;
  return __builtin_bit_cast(float, u);
}

// ---- ATf: A[t][4096][256] f32 -> frag-linear bf16 B-operand tiles ----
__global__ __launch_bounds__(256) void k_prep(const float* __restrict__ A,
                                              unsigned short* __restrict__ ATf) {
  __shared__ float sT[64][36];
  const int jgrp = blockIdx.x, ds = blockIdx.y, t = blockIdx.z;
  const int tid = threadIdx.x;
  const float* Ab = A + (size_t)t * N_PTS * DIM;
  {
    const int j_l = tid >> 2, dq = tid & 3;
    const float* src = Ab + (size_t)(jgrp * 64 + j_l) * DIM + ds * 32 + dq * 8;
    f32x4v v0 = *(const f32x4v*)src, v1 = *(const f32x4v*)(src + 4);
    *(f32x4v*)&sT[j_l][dq * 8] = v0;
    *(f32x4v*)&sT[j_l][dq * 8 + 4] = v1;
  }
  __syncthreads();
  const int jb_l = tid >> 6, l = tid & 63, l31 = l & 31, lhi = l >> 5;
  u16x8 o;
#pragma unroll
  for (int e = 0; e < 8; ++e) o[e] = f2bf(sT[jb_l * 16 + lhi * 8 + e][l31]);
  unsigned short* dst = ATf + (size_t)t * (8 * 256 * 64 * 8)
                      + ((size_t)(ds * 256 + jgrp * 4 + jb_l) * 64 + l) * 8;
  *(u16x8*)dst = o;
}

// eperm index for row r
__device__ __forceinline__ int pidx(int r) {
  const int jj = r & 31;
  return (r & ~31) | (((jj >> 2) & 1) << 4) | (((jj >> 3) & 3) << 2) | (jj & 3);
}

// ---- init: X -> Zf frags + erow + eperm ----
__global__ __launch_bounds__(256) void k_init(const float* __restrict__ X,
                                              unsigned short* __restrict__ Zf,
                                              float* __restrict__ erow,
                                              float* __restrict__ eperm) {
  const int tid = threadIdx.x;
  const int r = blockIdx.x * 8 + (tid >> 5), o = tid & 31;
  const size_t base = (size_t)r * DIM + o * 8;
  f32x4v z0 = *(const f32x4v*)(X + base), z1 = *(const f32x4v*)(X + base + 4);
  u16x8 zb; float s = 0.f;
#pragma unroll
  for (int i = 0; i < 4; ++i) { zb[i] = f2bf(z0[i]); zb[4 + i] = f2bf(z1[i]);
                                s += z0[i] * z0[i] + z1[i] * z1[i]; }
  *(u16x8*)(Zf + ((size_t)((r >> 5) * 16 + (o >> 1)) * 64 + (o & 1) * 32 + (r & 31)) * 8) = zb;
#pragma unroll
  for (int d = 16; d > 0; d >>= 1) s += __shfl_down(s, d, 32);
  if (o == 0) { const float e = __expf(-s * C1); erow[r] = e; eperm[pidx(r)] = e; }
}

// ---- fused flash, R13: barrier-free, LDS-free wave streaming ----
// grid (8 chunks, 64 i-blocks), 256 thr = 4 independent waves:
// ig=wid>>1 (32 i-rows), dh=wid&1 (128 d-cols). Zi resident in VGPRs.
// Zj a-frags streamed from L1/L2 via rolling 8-frag register window.
__global__ __launch_bounds__(256, 2) void k_flash(
    const unsigned short* __restrict__ Zf, const float* __restrict__ erow,
    const float* __restrict__ eperm,
    const unsigned short* __restrict__ ATf_t,
    const float* __restrict__ Aaff_t,
    unsigned short* __restrict__ Opart) {
  const int tid = threadIdx.x, lane = tid & 63, wid = tid >> 6;
  const int l31 = lane & 31, lhi = lane >> 5;
  const int ig = wid >> 1, dh = wid & 1;
  const int chunk = blockIdx.x;
  const int i0 = blockIdx.y * 64;

  // chunk's Zj frag stream: frag f (= tile*16 + ks) at zjs + f*512 + lane*8
  const unsigned short* zjs = Zf + (size_t)(chunk * 16) * 8192;

  // window prologue: issue frags 0..7 (loads stay in flight until first use)
  u32x4 zw[8];
#pragma unroll
  for (int f = 0; f < 8; ++f)
    zw[f] = *(const u32x4*)(zjs + (size_t)f * 512 + lane * 8);

  // resident Zi frags: wave's 32 i-rows x K=256 (static indices ONLY)
  const unsigned short* zib = Zf + (size_t)(blockIdx.y * 2 + ig) * 8192;
  u32x4 zi[16];
#pragma unroll
  for (int ks = 0; ks < 16; ++ks)
    zi[ks] = *(const u32x4*)(zib + (size_t)ks * 512 + lane * 8);

  const float eI = erow[i0 + ig * 32 + l31];

  // O init + affine slice (ksg = chunk*2+q, unscaled; summed across chunks).
  // a-frag re-read from GLOBAL: zi[runtime] would demote zi[] to scratch (R7).
  f32x16 O[4];
#pragma unroll
  for (int ct = 0; ct < 4; ++ct)
#pragma unroll
    for (int i = 0; i < 16; ++i) O[ct][i] = 0.f;
#pragma unroll
  for (int q = 0; q < 2; ++q) {
    const int ksg = chunk * 2 + q;
    const bf16x8 a = *(const bf16x8*)(zib + (size_t)ksg * 512 + lane * 8);
#pragma unroll
    for (int ct = 0; ct < 4; ++ct) {
      const int d = dh * 128 + ct * 32 + l31;
      const float* bp = Aaff_t + (size_t)d * DIM + ksg * 16 + lhi * 8;
      f32x4v f0 = *(const f32x4v*)bp, f1 = *(const f32x4v*)(bp + 4);
      u16x8 tb;
#pragma unroll
      for (int i = 0; i < 4; ++i) { tb[i] = f2bf(f0[i]); tb[4 + i] = f2bf(f1[i]); }
      O[ct] = __builtin_amdgcn_mfma_f32_32x32x16_bf16(
          a, __builtin_bit_cast(bf16x8, tb), O[ct], 0, 0, 0);
    }
  }

  const float* epc = eperm + (size_t)chunk * 512 + lhi * 16;
  const unsigned short* atb =
      ATf_t + ((size_t)(dh * 4 * 256 + chunk * 32) * 64 + lane) * 8;

  for (int n = 0; n < 16; ++n) {
    // ej + bw batch q=0 for this tile (consumed ~700cyc later, after S-chain)
    f32x4v e0 = *(const f32x4v*)(epc + n * 32);
    f32x4v e1 = *(const f32x4v*)(epc + n * 32 + 4);
    f32x4v e2 = *(const f32x4v*)(epc + n * 32 + 8);
    f32x4v e3 = *(const f32x4v*)(epc + n * 32 + 12);
    u32x4 bw0[4];
#pragma unroll
    for (int ct = 0; ct < 4; ++ct)
      bw0[ct] = *(const u32x4*)(atb + ((size_t)ct * 256 + n * 2 + 0) * 512);

    // S^T = Zj @ Zi^T : A = streamed window frag, B = zi (regs).
    // Consume zw[ks&7] (compiler inserts counted vmcnt), refill with frag
    // n*16+ks+8. Tail refills (f>=256) read <=8KB past Zf into erow region
    // of the same workspace — issued but never consumed (harmless).
    f32x16 Sa, Sb;
#pragma unroll
    for (int i = 0; i < 16; ++i) { Sa[i] = 0.f; Sb[i] = 0.f; }
    __builtin_amdgcn_s_setprio(1);
#pragma unroll
    for (int ks = 0; ks < 16; ks += 2) {
      const bf16x8 a0 = __builtin_bit_cast(bf16x8, zw[ks & 7]);
      const bf16x8 a1 = __builtin_bit_cast(bf16x8, zw[(ks + 1) & 7]);
      Sa = __builtin_amdgcn_mfma_f32_32x32x16_bf16(a0, __builtin_bit_cast(bf16x8, zi[ks + 0]), Sa, 0, 0, 0);
      Sb = __builtin_amdgcn_mfma_f32_32x32x16_bf16(a1, __builtin_bit_cast(bf16x8, zi[ks + 1]), Sb, 0, 0, 0);
      zw[ks & 7]       = *(const u32x4*)(zjs + (size_t)(n * 16 + ks + 8) * 512 + lane * 8);
      zw[(ks + 1) & 7] = *(const u32x4*)(zjs + (size_t)(n * 16 + ks + 9) * 512 + lane * 8);
    }
    __builtin_amdgcn_s_setprio(0);

    // bw batch q=1 — latency hides under exp/pack + q0 PV
    u32x4 bw1[4];
#pragma unroll
    for (int ct = 0; ct < 4; ++ct)
      bw1[ct] = *(const u32x4*)(atb + ((size_t)ct * 256 + n * 2 + 1) * 512);

    // P^T: lane=(i,lhi), reg c -> j = n*32 + (c&3)+8*(c>>2)+4*lhi.
    // R8-verified math (eI*ej*expf), R7-verified cvt_pk pack.
    float p[16];
#pragma unroll
    for (int c = 0; c < 16; ++c) {
      const float ej = (c < 4) ? e0[c] : (c < 8) ? e1[c - 4]
                     : (c < 12) ? e2[c - 8] : e3[c - 12];
      p[c] = eI * ej * __expf((Sa[c] + Sb[c]) * C2);
    }
    unsigned int dw[4][2];
#pragma unroll
    for (int g = 0; g < 4; ++g) {
      asm("v_cvt_pk_bf16_f32 %0, %1, %2" : "=v"(dw[g][0]) : "v"(p[4 * g + 0]), "v"(p[4 * g + 1]));
      asm("v_cvt_pk_bf16_f32 %0, %1, %2" : "=v"(dw[g][1]) : "v"(p[4 * g + 2]), "v"(p[4 * g + 3]));
    }
    // permlane32_swap: x_new={x_lo,y_lo} -> frag words (e0..3), y_new -> (e4..7)
    {
      auto r0 = __builtin_amdgcn_permlane32_swap(dw[0][0], dw[1][0], false, false);
      auto r1 = __builtin_amdgcn_permlane32_swap(dw[0][1], dw[1][1], false, false);
      u32x4 paw; paw[0] = r0[0]; paw[1] = r1[0]; paw[2] = r0[1]; paw[3] = r1[1];
      const bf16x8 pa = __builtin_bit_cast(bf16x8, paw);
      __builtin_amdgcn_s_setprio(1);
#pragma unroll
      for (int ct = 0; ct < 4; ++ct)
        O[ct] = __builtin_amdgcn_mfma_f32_32x32x16_bf16(
            pa, __builtin_bit_cast(bf16x8, bw0[ct]), O[ct], 0, 0, 0);
      __builtin_amdgcn_s_setprio(0);
    }
    {
      auto r0 = __builtin_amdgcn_permlane32_swap(dw[2][0], dw[3][0], false, false);
      auto r1 = __builtin_amdgcn_permlane32_swap(dw[2][1], dw[3][1], false, false);
      u32x4 paw; paw[0] = r0[0]; paw[1] = r1[0]; paw[2] = r0[1]; paw[3] = r1[1];
      const bf16x8 pa = __builtin_bit_cast(bf16x8, paw);
      __builtin_amdgcn_s_setprio(1);
#pragma unroll
      for (int ct = 0; ct < 4; ++ct)
        O[ct] = __builtin_amdgcn_mfma_f32_32x32x16_bf16(
            pa, __builtin_bit_cast(bf16x8, bw1[ct]), O[ct], 0, 0, 0);
      __builtin_amdgcn_s_setprio(0);
    }
  }

  // epilogue -> Opart[chunk] bf16 (P already carries ei*ej)
  unsigned short* ob = Opart + (size_t)chunk * N_PTS * DIM
                     + (size_t)(i0 + ig * 32) * DIM + dh * 128 + l31;
#pragma unroll
  for (int ct = 0; ct < 4; ++ct)
#pragma unroll
    for (int c = 0; c < 16; ++c) {
      const int row = 4 * lhi + (c & 3) + 8 * (c >> 2);
      ob[(size_t)row * DIM + ct * 32] = f2bf(O[ct][c]);
    }
}

// ---- update: Z += DT*(sum partials + baff); emit Zf frags + erow + eperm ----
__global__ __launch_bounds__(256) void k_update(const float* __restrict__ Zin,
                                                const unsigned short* __restrict__ Opart,
                                                const float* __restrict__ baff_t,
                                                float* __restrict__ Zout,
                                                unsigned short* __restrict__ Zf,
                                                float* __restrict__ erow,
                                                float* __restrict__ eperm) {
  const int tid = threadIdx.x;
  const int r = blockIdx.x * 8 + (tid >> 5), o = tid & 31;
  const size_t base = (size_t)r * DIM + o * 8;
  f32x4v z0 = *(const f32x4v*)(Zin + base), z1 = *(const f32x4v*)(Zin + base + 4);
  f32x4v s0 = *(const f32x4v*)(baff_t + o * 8), s1 = *(const f32x4v*)(baff_t + o * 8 + 4);
#pragma unroll
  for (int c = 0; c < 8; ++c) {
    u16x8 p = *(const u16x8*)(Opart + (size_t)c * N_PTS * DIM + base);
#pragma unroll
    for (int i = 0; i < 4; ++i) { s0[i] += bf2f(p[i]); s1[i] += bf2f(p[4 + i]); }
  }
  u16x8 zb; float sv = 0.f;
#pragma unroll
  for (int i = 0; i < 4; ++i) {
    z0[i] += DT_C * s0[i]; z1[i] += DT_C * s1[i];
    zb[i] = f2bf(z0[i]); zb[4 + i] = f2bf(z1[i]);
    sv += z0[i] * z0[i] + z1[i] * z1[i];
  }
  *(f32x4v*)(Zout + base) = z0;
  *(f32x4v*)(Zout + base + 4) = z1;
  *(u16x8*)(Zf + ((size_t)((r >> 5) * 16 + (o >> 1)) * 64 + (o & 1) * 32 + (r & 31)) * 8) = zb;
#pragma unroll
  for (int d = 16; d > 0; d >>= 1) sv += __shfl_down(sv, d, 32);
  if (o == 0) { const float e = __expf(-sv * C1); erow[r] = e; eperm[pidx(r)] = e; }
}

extern "C" void kernel_launch(void* const* d_in, const int* in_sizes, int n_in,
                              void* d_out, int out_size, void* d_ws, size_t ws_size,
                              hipStream_t stream) {
  const float* X    = (const float*)d_in[0];
  const float* A    = (const float*)d_in[1];
  const float* Aaff = (const float*)d_in[2];
  const float* baff = (const float*)d_in[3];
  float* out = (float*)d_out;

  char* w = (char*)d_ws;
  size_t off = 0;
  unsigned short* ATf = (unsigned short*)(w + off); off += (size_t)8 * 8 * 256 * 64 * 8 * 2; // 16 MiB
  unsigned short* Zf  = (unsigned short*)(w + off); off += (size_t)N_PTS * DIM * 2;          // 2 MiB
  float* erow  = (float*)(w + off); off += (size_t)N_PTS * 4;   // (also absorbs tile-15 window overread)
  float* eperm = (float*)(w + off); off += (size_t)N_PTS * 4;
  float* Zf32 = (float*)(w + off); off += (size_t)N_PTS * DIM * 4;                           // 4 MiB
  unsigned short* Opart = (unsigned short*)(w + off); off += (size_t)8 * N_PTS * DIM * 2;    // 16 MiB
  (void)ws_size; (void)in_sizes; (void)n_in; (void)out_size;

  k_prep<<<dim3(64, 8, 8), 256, 0, stream>>>(A, ATf);
  k_init<<<512, 256, 0, stream>>>(X, Zf, erow, eperm);

  const float* zin = X;
  for (int t = 0; t < 8; ++t) {
    float* zout = (t == 7) ? out : Zf32;  // in-place safe after t=0
    k_flash<<<dim3(8, 64), 256, 0, stream>>>(
        Zf, erow, eperm, ATf + (size_t)t * (8 * 256 * 64 * 8), Aaff + (size_t)t * DIM * DIM, Opart);
    k_update<<<512, 256, 0, stream>>>(zin, Opart, baff + (size_t)t * DIM, zout, Zf, erow, eperm);
    zin = zout;
  }
}

// Round 9
// 366.834 us; speedup vs baseline: 2.1491x; 2.1491x over previous
//
#include <hip/hip_runtime.h>

// DiffeomorphicLearnerTorch, R14 = R6 (session-best, 381us verified) + T5 setprio.
// R7-R13 retrospective: the symmetric swapped-operand structure (in-register
// softmax via cvt_pk+permlane) spanned reg-diet (R8), operand L2->LDS (R11),
// counted-vmcnt 4-deep ring (R12), barrier-free streaming (R13, spilled:
// WRITE 16->40MB scratch) — every correct variant 43.5-44.5us vs R6's 40.2.
// Two different structures pinned at ~40-44 with all pipes <=26% busy =>
// revert to best-known-good. One session lesson DOES match R6's regime:
// s_setprio around MFMA clusters pays in ROLE-SPLIT wave mixes (producer/
// consumer on same SIMD, 4 waves/SIMD here) per m191 (+4-7% attn), null in
// lockstep-symmetric mixes (m190) — which is why it couldn't help R8-R13.
// Scheduling-only => value-identical to R6's verified math.
// Per step: Z += DT*(Z@Aaff^T + b + [ei*ej*exp(2*C1*Z@Z^T)]@A_t)
// Frag-linear layouts (verified R4/R5):
//   Zf  [128 jblk][16 ks][64 lane]x8 bf16
//   ATf [t][8 dblk][256 jb][64 lane]x8 bf16

#define N_PTS 4096
#define DIM   256
#define DT_C  0.125f
#define C1    (1.0f/512.0f)

typedef __bf16 bf16x8 __attribute__((ext_vector_type(8)));
typedef float  f32x16 __attribute__((ext_vector_type(16)));
typedef float  f32x4v __attribute__((ext_vector_type(4)));
typedef unsigned int   u32x4 __attribute__((ext_vector_type(4)));
typedef unsigned short u16x8 __attribute__((ext_vector_type(8)));

__device__ __forceinline__ unsigned short f2bf(float f) {
  unsigned int u = __builtin_bit_cast(unsigned int, f);
  u += 0x7fffu + ((u >> 16) & 1u);          // RNE
  return (unsigned short)(u >> 16);
}
__device__ __forceinline__ float bf2f(unsigned short s) {
  unsigned int u = ((unsigned int)s) << 16;
  return __builtin_bit_cast(float, u);
}

// ---- ATf: A[t][4096][256] f32 -> frag-linear bf16 B-operand tiles ----
__global__ __launch_bounds__(256) void k_prep(const float* __restrict__ A,
                                              unsigned short* __restrict__ ATf) {
  __shared__ float sT[64][36];
  const int jgrp = blockIdx.x, ds = blockIdx.y, t = blockIdx.z;
  const int tid = threadIdx.x;
  const float* Ab = A + (size_t)t * N_PTS * DIM;
  {
    const int j_l = tid >> 2, dq = tid & 3;
    const float* src = Ab + (size_t)(jgrp * 64 + j_l) * DIM + ds * 32 + dq * 8;
    f32x4v v0 = *(const f32x4v*)src, v1 = *(const f32x4v*)(src + 4);
    *(f32x4v*)&sT[j_l][dq * 8] = v0;
    *(f32x4v*)&sT[j_l][dq * 8 + 4] = v1;
  }
  __syncthreads();
  const int jb_l = tid >> 6, l = tid & 63, l31 = l & 31, lhi = l >> 5;
  u16x8 o;
#pragma unroll
  for (int e = 0; e < 8; ++e) o[e] = f2bf(sT[jb_l * 16 + lhi * 8 + e][l31]);
  unsigned short* dst = ATf + (size_t)t * (8 * 256 * 64 * 8)
                      + ((size_t)(ds * 256 + jgrp * 4 + jb_l) * 64 + l) * 8;
  *(u16x8*)dst = o;
}

// ---- init: X -> Zf frags + erow ----
__global__ __launch_bounds__(256) void k_init(const float* __restrict__ X,
                                              unsigned short* __restrict__ Zf,
                                              float* __restrict__ erow) {
  const int tid = threadIdx.x;
  const int r = blockIdx.x * 8 + (tid >> 5), o = tid & 31;
  const size_t base = (size_t)r * DIM + o * 8;
  f32x4v z0 = *(const f32x4v*)(X + base), z1 = *(const f32x4v*)(X + base + 4);
  u16x8 zb; float s = 0.f;
#pragma unroll
  for (int i = 0; i < 4; ++i) { zb[i] = f2bf(z0[i]); zb[4 + i] = f2bf(z1[i]);
                                s += z0[i] * z0[i] + z1[i] * z1[i]; }
  *(u16x8*)(Zf + ((size_t)((r >> 5) * 16 + (o >> 1)) * 64 + (o & 1) * 32 + (r & 31)) * 8) = zb;
#pragma unroll
  for (int d = 16; d > 0; d >>= 1) s += __shfl_down(s, d, 32);
  if (o == 0) erow[r] = __expf(-s * C1);
}

// ---- fused flash (R6 structure) ----
// grid (8 chunks, 64 i-tiles of 64 rows), 512 thr = 8 waves, 2 blocks/CU.
// waves 0-3 producer (ip=wid>>1, jh=wid&1): S = Zi(32) @ Zj(32)^T;
//   af from sZi (LDS), b-frags hoisted x16 from global. P -> sP[n&1].
// waves 4-7 consumer cd: O(64i x 64d) += P @ A_t; b hoisted x8 from global;
//   + affine slice ksg=chunk*2+{0,1} (a-frags from sZi).
// R14: setprio(1) around producer-S and consumer-PV MFMA clusters (T5,
// role-split regime).
__global__ __launch_bounds__(512, 4) void k_flash(
    const unsigned short* __restrict__ Zf, const float* __restrict__ erow,
    const unsigned short* __restrict__ ATf_t,
    const float* __restrict__ Aaff_t,
    unsigned short* __restrict__ Opart) {
  __shared__ __align__(16) unsigned short sZi[64 * 256];   // 32KB frag-linear
  __shared__ __align__(16) unsigned short sP[2][64 * 64];  // 2 x 8KB swizzled

  const int tid = threadIdx.x, lane = tid & 63, wid = tid >> 6;
  const int l31 = lane & 31, lhi = lane >> 5;
  const int chunk = blockIdx.x;
  const int i0 = blockIdx.y * 64;
  const int ib = i0 >> 5;

  // stage sZi: 32KB contiguous slice of Zf (frag-linear already)
  {
    const unsigned short* src = Zf + (size_t)ib * 8192;
#pragma unroll
    for (int p = 0; p < 4; ++p)
      *(u32x4*)(sZi + (size_t)(p * 512 + tid) * 8) =
          *(const u32x4*)(src + (size_t)(p * 512 + tid) * 8);
  }
  __syncthreads();

  if (wid < 4) {
    // ================= producer =================
    const int ip = wid >> 1, jh = wid & 1;
    float eI[16];
#pragma unroll
    for (int c = 0; c < 16; ++c)
      eI[c] = erow[i0 + ip * 32 + 4 * lhi + (c & 3) + 8 * (c >> 2)];

    for (int n = 0; n < 8; ++n) {
      // hoist all 16 b-frags (MLP=16)
      u32x4 bv[16];
      {
        const unsigned short* bp =
            Zf + ((size_t)(chunk * 16 + n * 2 + jh) * 16 * 64 + lane) * 8;
#pragma unroll
        for (int ks = 0; ks < 16; ++ks) bv[ks] = *(const u32x4*)(bp + ks * 512);
      }
      f32x16 S;
#pragma unroll
      for (int i = 0; i < 16; ++i) S[i] = 0.f;
      __builtin_amdgcn_s_setprio(1);
#pragma unroll
      for (int ks = 0; ks < 16; ++ks) {
        bf16x8 af = *(const bf16x8*)(sZi + ((size_t)(ip * 16 + ks) * 64 + lane) * 8);
        S = __builtin_amdgcn_mfma_f32_32x32x16_bf16(af, __builtin_bit_cast(bf16x8, bv[ks]), S, 0, 0, 0);
      }
      __builtin_amdgcn_s_setprio(0);
      const float ej = erow[chunk * 512 + n * 64 + jh * 32 + l31];
      unsigned short* pb = sP[n & 1];
      const int blk = jh * 4 + (l31 >> 3), cl = l31 & 7;
#pragma unroll
      for (int c = 0; c < 16; ++c) {
        const int row = ip * 32 + 4 * lhi + (c & 3) + 8 * (c >> 2);
        pb[row * 64 + ((blk ^ (row & 7)) * 8) + cl] =
            f2bf(eI[c] * ej * __expf(2.f * C1 * S[c]));
      }
      __syncthreads();
    }
    __syncthreads();   // match consumer's 9th barrier
  } else {
    // ================= consumer =================
    const int cd = wid - 4;
    f32x16 O[2][2];
#pragma unroll
    for (int rs = 0; rs < 2; ++rs)
#pragma unroll
      for (int ct = 0; ct < 2; ++ct)
#pragma unroll
        for (int i = 0; i < 16; ++i) O[rs][ct][i] = 0.f;

    // affine slice (unscaled): ksg = chunk*2 + {0,1}; a-frags from sZi
#pragma unroll
    for (int q = 0; q < 2; ++q) {
      const int ksg = chunk * 2 + q;
      bf16x8 a[2];
#pragma unroll
      for (int rs = 0; rs < 2; ++rs)
        a[rs] = *(const bf16x8*)(sZi + ((size_t)(rs * 16 + ksg) * 64 + lane) * 8);
#pragma unroll
      for (int ct = 0; ct < 2; ++ct) {
        const int d = cd * 64 + ct * 32 + l31;
        const float* bp = Aaff_t + (size_t)d * DIM + ksg * 16 + lhi * 8;
        f32x4v f0 = *(const f32x4v*)bp, f1 = *(const f32x4v*)(bp + 4);
        u16x8 tb;
#pragma unroll
        for (int i = 0; i < 4; ++i) { tb[i] = f2bf(f0[i]); tb[4 + i] = f2bf(f1[i]); }
        bf16x8 bv = __builtin_bit_cast(bf16x8, tb);
#pragma unroll
        for (int rs = 0; rs < 2; ++rs)
          O[rs][ct] = __builtin_amdgcn_mfma_f32_32x32x16_bf16(a[rs], bv, O[rs][ct], 0, 0, 0);
      }
    }
    __syncthreads();   // barrier 1 (producer finished tile 0)

    for (int n = 1; n <= 8; ++n) {
      const int m = n - 1;
      // hoist the 8 ATf b-frags (MLP=8)
      u32x4 bw[8];
#pragma unroll
      for (int ks = 0; ks < 4; ++ks)
#pragma unroll
        for (int ct = 0; ct < 2; ++ct)
          bw[ks * 2 + ct] = *(const u32x4*)(ATf_t +
              ((size_t)((cd * 2 + ct) * 256 + chunk * 32 + m * 4 + ks) * 64 + lane) * 8);
      const unsigned short* pb = sP[m & 1];
#pragma unroll
      for (int ks = 0; ks < 4; ++ks) {
        bf16x8 a[2];
        const int blk = ks * 2 + lhi;
#pragma unroll
        for (int rs = 0; rs < 2; ++rs) {
          const int row = rs * 32 + l31;
          a[rs] = *(const bf16x8*)&pb[row * 64 + ((blk ^ (row & 7)) * 8)];
        }
        __builtin_amdgcn_s_setprio(1);
#pragma unroll
        for (int rs = 0; rs < 2; ++rs)
#pragma unroll
          for (int ct = 0; ct < 2; ++ct)
            O[rs][ct] = __builtin_amdgcn_mfma_f32_32x32x16_bf16(
                a[rs], __builtin_bit_cast(bf16x8, bw[ks * 2 + ct]), O[rs][ct], 0, 0, 0);
        __builtin_amdgcn_s_setprio(0);
      }
      __syncthreads();
    }

    // epilogue -> Opart[chunk] bf16 (P already carries ei*ej)
    unsigned short* ob = Opart + (size_t)chunk * N_PTS * DIM + (size_t)cd * 64 + l31;
#pragma unroll
    for (int rs = 0; rs < 2; ++rs)
#pragma unroll
      for (int c = 0; c < 16; ++c) {
        const int row = i0 + rs * 32 + 4 * lhi + (c & 3) + 8 * (c >> 2);
        ob[(size_t)row * DIM]      = f2bf(O[rs][0][c]);
        ob[(size_t)row * DIM + 32] = f2bf(O[rs][1][c]);
      }
  }
}

// ---- update: Z += DT*(sum partials + baff); emit Zf frags + erow ----
__global__ __launch_bounds__(256) void k_update(const float* __restrict__ Zin,
                                                const unsigned short* __restrict__ Opart,
                                                const float* __restrict__ baff_t,
                                                float* __restrict__ Zout,
                                                unsigned short* __restrict__ Zf,
                                                float* __restrict__ erow) {
  const int tid = threadIdx.x;
  const int r = blockIdx.x * 8 + (tid >> 5), o = tid & 31;
  const size_t base = (size_t)r * DIM + o * 8;
  f32x4v z0 = *(const f32x4v*)(Zin + base), z1 = *(const f32x4v*)(Zin + base + 4);
  f32x4v s0 = *(const f32x4v*)(baff_t + o * 8), s1 = *(const f32x4v*)(baff_t + o * 8 + 4);
#pragma unroll
  for (int c = 0; c < 8; ++c) {
    u16x8 p = *(const u16x8*)(Opart + (size_t)c * N_PTS * DIM + base);
#pragma unroll
    for (int i = 0; i < 4; ++i) { s0[i] += bf2f(p[i]); s1[i] += bf2f(p[4 + i]); }
  }
  u16x8 zb; float sv = 0.f;
#pragma unroll
  for (int i = 0; i < 4; ++i) {
    z0[i] += DT_C * s0[i]; z1[i] += DT_C * s1[i];
    zb[i] = f2bf(z0[i]); zb[4 + i] = f2bf(z1[i]);
    sv += z0[i] * z0[i] + z1[i] * z1[i];
  }
  *(f32x4v*)(Zout + base) = z0;
  *(f32x4v*)(Zout + base + 4) = z1;
  *(u16x8*)(Zf + ((size_t)((r >> 5) * 16 + (o >> 1)) * 64 + (o & 1) * 32 + (r & 31)) * 8) = zb;
#pragma unroll
  for (int d = 16; d > 0; d >>= 1) sv += __shfl_down(sv, d, 32);
  if (o == 0) erow[r] = __expf(-sv * C1);
}

extern "C" void kernel_launch(void* const* d_in, const int* in_sizes, int n_in,
                              void* d_out, int out_size, void* d_ws, size_t ws_size,
                              hipStream_t stream) {
  const float* X    = (const float*)d_in[0];
  const float* A    = (const float*)d_in[1];
  const float* Aaff = (const float*)d_in[2];
  const float* baff = (const float*)d_in[3];
  float* out = (float*)d_out;

  char* w = (char*)d_ws;
  size_t off = 0;
  unsigned short* ATf = (unsigned short*)(w + off); off += (size_t)8 * 8 * 256 * 64 * 8 * 2; // 16 MiB
  unsigned short* Zf  = (unsigned short*)(w + off); off += (size_t)N_PTS * DIM * 2;          // 2 MiB
  float* erow = (float*)(w + off); off += (size_t)N_PTS * 4;
  float* Zf32 = (float*)(w + off); off += (size_t)N_PTS * DIM * 4;                           // 4 MiB
  unsigned short* Opart = (unsigned short*)(w + off); off += (size_t)8 * N_PTS * DIM * 2;    // 16 MiB
  (void)ws_size; (void)in_sizes; (void)n_in; (void)out_size;

  k_prep<<<dim3(64, 8, 8), 256, 0, stream>>>(A, ATf);
  k_init<<<512, 256, 0, stream>>>(X, Zf, erow);

  const float* zin = X;
  for (int t = 0; t < 8; ++t) {
    float* zout = (t == 7) ? out : Zf32;  // in-place safe after t=0
    k_flash<<<dim3(8, 64), 512, 0, stream>>>(
        Zf, erow, ATf + (size_t)t * (8 * 256 * 64 * 8), Aaff + (size_t)t * DIM * DIM, Opart);
    k_update<<<512, 256, 0, stream>>>(zin, Opart, baff + (size_t)t * DIM, zout, Zf, erow);
    zin = zout;
  }
}